// Round 1
// 64.212 us; speedup vs baseline: 1.0436x; 1.0436x over previous
//
#include <hip/hip_runtime.h>

#define BATCH 1024
#define LEN   512
#define NTHREADS 256
#define MARGIN 1.0f

// Kernel 1: one block per sample. Ballot-compact pos/neg into LDS,
// tile the (pos x neg) hinge sum with 64x64 tiles, block-reduce, store ws[b].
//
// R3 change vs previous best (66.9us):
//  - Tile 256x64 -> 64x64. Pos padded to mult-of-64 (was 256). ~49% of
//    blocks had n_pos in (256,512] and padded to 512 -> 1.7x VALU inflation;
//    now E[padded pairs] ~83K vs 110K (-25%).
//  - 15-25 tiles/block (was 4-8): staggered 2D partition balances waves to
//    +-1 tile and kills the runtime `t / nchunks` division in the tile loop.
//  - Same 3-op fmaxf pair math, same sentinel trick (branch-free tiles).
// No atomics to global: 1024-way same-address atomicAdd measured +7us (R2).
__global__ __launch_bounds__(NTHREADS) void per_sample_loss(
    const float* __restrict__ scores,   // [BATCH, LEN]
    const int*   __restrict__ labels,   // [BATCH, LEN], nonzero = positive
    float*       __restrict__ ws)       // [BATCH] per-sample loss
{
    __shared__ __align__(16) float pos[LEN];
    __shared__ __align__(16) float neg[LEN];
    __shared__ int cnt[2];              // [0]=n_pos, [1]=n_neg
    __shared__ float red[NTHREADS / 64];

    const int b    = blockIdx.x;
    const int tid  = threadIdx.x;
    const int lane = tid & 63;
    const int wave = tid >> 6;

    if (tid < 2) cnt[tid] = 0;
    __syncthreads();

    // ---- Compaction: wave ballot + prefix popcount, 2 LDS atomics/wave/iter.
    const unsigned long long lt_mask = (1ull << lane) - 1ull;
    #pragma unroll
    for (int iter = 0; iter < LEN / NTHREADS; ++iter) {
        const int l  = tid + iter * NTHREADS;
        const float s  = scores[b * LEN + l];
        const int   la = labels[b * LEN + l];
        const bool isp = (la != 0);

        const unsigned long long mp = __ballot(isp);
        const int np_wave = __popcll(mp);

        int basep = 0, basen = 0;
        if (lane == 0) {
            basep = atomicAdd(&cnt[0], np_wave);
            basen = atomicAdd(&cnt[1], 64 - np_wave);
        }
        basep = __shfl(basep, 0, 64);
        basen = __shfl(basen, 0, 64);

        if (isp) pos[basep + __popcll(mp  & lt_mask)] = s;
        else     neg[basen + __popcll(~mp & lt_mask)] = s;
    }
    __syncthreads();

    const int n_pos = cnt[0];
    const int n_neg = cnt[1];

    // ---- Sentinel-pad both sides to multiple of 64 so tiles are branch-free.
    // pos sentinel +1e30 -> q = 1 - 1e30 hugely negative -> contributes 0.
    // neg sentinel -1e30 -> q + n hugely negative -> contributes 0.
    // (q+n worst case -2e30: finite in fp32, no inf/nan.)
    const int npos_pad = (n_pos + 63) & ~63;
    const int nneg_pad = (n_neg + 63) & ~63;
    for (int i = n_pos + tid; i < npos_pad; i += NTHREADS) pos[i] =  1e30f;
    for (int i = n_neg + tid; i < nneg_pad; i += NTHREADS) neg[i] = -1e30f;
    __syncthreads();

    // ---- Tiled pair loop, 64x64 tiles.
    // Each wave handles tiles (pc, nc) with nc = (wave+pc) mod 4 stepping 4:
    // covers every tile exactly once across the 4 waves, balanced to +-1 tile,
    // no runtime division. Per pc-row: 1 ds_read_b32 for the lane's positive
    // (64 consecutive floats -> conflict-free), q hoisted; per tile: 16
    // broadcast ds_read_b128 for the neg chunk -> 64 pairs/lane, 3 VALU/pair.
    const int pchunks = npos_pad >> 6;
    const int nchunks = nneg_pad >> 6;

    float a0 = 0.f, a1 = 0.f, a2 = 0.f, a3 = 0.f;
    const float4* neg4 = reinterpret_cast<const float4*>(neg);

    for (int pc = 0; pc < pchunks; ++pc) {
        const float p = pos[(pc << 6) + lane];
        const float q = MARGIN - p;

        for (int nc = (wave + pc) & 3; nc < nchunks; nc += 4) {
            const float4* nb = neg4 + (nc << 4);
            #pragma unroll
            for (int j = 0; j < 16; j += 4) {
                const float4 n0 = nb[j];
                const float4 n1 = nb[j + 1];
                const float4 n2 = nb[j + 2];
                const float4 n3 = nb[j + 3];
                a0 += fmaxf(0.f, q + n0.x) + fmaxf(0.f, q + n0.y)
                    + fmaxf(0.f, q + n0.z) + fmaxf(0.f, q + n0.w);
                a1 += fmaxf(0.f, q + n1.x) + fmaxf(0.f, q + n1.y)
                    + fmaxf(0.f, q + n1.z) + fmaxf(0.f, q + n1.w);
                a2 += fmaxf(0.f, q + n2.x) + fmaxf(0.f, q + n2.y)
                    + fmaxf(0.f, q + n2.z) + fmaxf(0.f, q + n2.w);
                a3 += fmaxf(0.f, q + n3.x) + fmaxf(0.f, q + n3.y)
                    + fmaxf(0.f, q + n3.z) + fmaxf(0.f, q + n3.w);
            }
        }
    }

    float acc = (a0 + a1) + (a2 + a3);

    // ---- Wave shuffle reduce, then across the 4 waves, single store.
    #pragma unroll
    for (int off = 32; off > 0; off >>= 1) acc += __shfl_down(acc, off, 64);
    if (lane == 0) red[wave] = acc;
    __syncthreads();

    if (tid == 0) {
        const float s = (red[0] + red[1]) + (red[2] + red[3]);
        const float n_pairs = (float)n_pos * (float)n_neg;
        ws[b] = s / fmaxf(n_pairs, 1.0f);
    }
}

// Kernel 2: deterministic reduction of BATCH per-sample losses -> mean.
// One float4 per thread (256 x 4 = 1024).
__global__ __launch_bounds__(NTHREADS) void reduce_batch(
    const float* __restrict__ ws, float* __restrict__ out)
{
    __shared__ float red[NTHREADS / 64];
    const int tid  = threadIdx.x;
    const int lane = tid & 63;
    const int wave = tid >> 6;

    const float4 v = reinterpret_cast<const float4*>(ws)[tid];
    float acc = (v.x + v.y) + (v.z + v.w);

    #pragma unroll
    for (int off = 32; off > 0; off >>= 1) acc += __shfl_down(acc, off, 64);
    if (lane == 0) red[wave] = acc;
    __syncthreads();

    if (tid == 0) {
        out[0] = ((red[0] + red[1]) + (red[2] + red[3])) * (1.0f / (float)BATCH);
    }
}

extern "C" void kernel_launch(void* const* d_in, const int* in_sizes, int n_in,
                              void* d_out, int out_size, void* d_ws, size_t ws_size,
                              hipStream_t stream) {
    const float* scores = (const float*)d_in[0];
    const int*   labels = (const int*)d_in[1];
    float*       out    = (float*)d_out;
    float*       ws     = (float*)d_ws;   // BATCH floats of scratch

    per_sample_loss<<<BATCH, NTHREADS, 0, stream>>>(scores, labels, ws);
    reduce_batch<<<1, NTHREADS, 0, stream>>>(ws, out);
}

// Round 2
// 63.337 us; speedup vs baseline: 1.0580x; 1.0138x over previous
//
#include <hip/hip_runtime.h>

#define BATCH 1024
#define LEN   512
#define NTHREADS 256
#define MARGIN 1.0f

typedef float v2f __attribute__((ext_vector_type(2)));

// Kernel 1: one block per sample. Ballot-compact pos/neg into LDS,
// tile the (pos x neg) hinge sum, block-reduce, store ws[b].
//
// R4 changes vs R3 (64.2us):
//  - Packed fp32 inner loop: float2 ext-vector ops -> v_pk_add_f32 /
//    v_pk_max_f32 (VOP3P), 2 pairs per VALU instr (was 1). Cuts pair-loop
//    instruction count 33-50% if pk issues at scalar rate on CDNA4.
//  - Neg tile granularity 64 -> 16 floats (4 x float4): E[padded pairs]
//    82K -> 75K (-9%).
//  - Same sentinel trick, same staggered wave partition (no runtime div).
// No atomics to global: 1024-way same-address atomicAdd measured +7us (R2).
__global__ __launch_bounds__(NTHREADS) void per_sample_loss(
    const float* __restrict__ scores,   // [BATCH, LEN]
    const int*   __restrict__ labels,   // [BATCH, LEN], nonzero = positive
    float*       __restrict__ ws)       // [BATCH] per-sample loss
{
    __shared__ __align__(16) float pos[LEN];
    __shared__ __align__(16) float neg[LEN];
    __shared__ int cnt[2];              // [0]=n_pos, [1]=n_neg
    __shared__ float red[NTHREADS / 64];

    const int b    = blockIdx.x;
    const int tid  = threadIdx.x;
    const int lane = tid & 63;
    const int wave = tid >> 6;

    if (tid < 2) cnt[tid] = 0;
    __syncthreads();

    // ---- Compaction: wave ballot + prefix popcount, 2 LDS atomics/wave/iter.
    const unsigned long long lt_mask = (1ull << lane) - 1ull;
    #pragma unroll
    for (int iter = 0; iter < LEN / NTHREADS; ++iter) {
        const int l  = tid + iter * NTHREADS;
        const float s  = scores[b * LEN + l];
        const int   la = labels[b * LEN + l];
        const bool isp = (la != 0);

        const unsigned long long mp = __ballot(isp);
        const int np_wave = __popcll(mp);

        int basep = 0, basen = 0;
        if (lane == 0) {
            basep = atomicAdd(&cnt[0], np_wave);
            basen = atomicAdd(&cnt[1], 64 - np_wave);
        }
        basep = __shfl(basep, 0, 64);
        basen = __shfl(basen, 0, 64);

        if (isp) pos[basep + __popcll(mp  & lt_mask)] = s;
        else     neg[basen + __popcll(~mp & lt_mask)] = s;
    }
    __syncthreads();

    const int n_pos = cnt[0];
    const int n_neg = cnt[1];

    // ---- Sentinel-pad: pos to mult-of-64 (lane dim), neg to mult-of-16
    // (inner-loop granularity, keeps float4 alignment).
    // pos sentinel +1e30 -> q = 1 - 1e30 hugely negative -> contributes 0.
    // neg sentinel -1e30 -> q + n hugely negative -> contributes 0.
    // (q+n worst case -2e30: finite in fp32, no inf/nan.)
    const int npos_pad = (n_pos + 63) & ~63;
    const int nneg_pad = (n_neg + 15) & ~15;
    for (int i = n_pos + tid; i < npos_pad; i += NTHREADS) pos[i] =  1e30f;
    for (int i = n_neg + tid; i < nneg_pad; i += NTHREADS) neg[i] = -1e30f;
    __syncthreads();

    // ---- Tiled pair loop, 64(pos lanes) x 16(neg) tiles.
    // Wave w at pos-chunk pc handles nc = ((w+pc)&3), +4, +8, ... -> every
    // (pc,nc) covered exactly once across 4 waves, balanced +-1, no runtime
    // division. Per tile: 4 broadcast ds_read_b128 + packed-fp32 hinge:
    // per float4 {2 pk_add, 2 pk_max, 2 pk_add} = 6 VOP3P / 4 pairs.
    const int pchunks = npos_pad >> 6;
    const int nchunks = nneg_pad >> 4;

    v2f acc0 = {0.f, 0.f}, acc1 = {0.f, 0.f};
    v2f acc2 = {0.f, 0.f}, acc3 = {0.f, 0.f};
    const v2f zero = {0.f, 0.f};
    const float4* neg4 = reinterpret_cast<const float4*>(neg);

    for (int pc = 0; pc < pchunks; ++pc) {
        const float q = MARGIN - pos[(pc << 6) + lane];
        const v2f qq = {q, q};

        for (int nc = (wave + pc) & 3; nc < nchunks; nc += 4) {
            const float4* nb = neg4 + (nc << 2);   // 16 floats = 4 float4
            #pragma unroll
            for (int j = 0; j < 4; j += 2) {
                const float4 n0 = nb[j];
                const float4 n1 = nb[j + 1];
                const v2f n0lo = {n0.x, n0.y}, n0hi = {n0.z, n0.w};
                const v2f n1lo = {n1.x, n1.y}, n1hi = {n1.z, n1.w};
                acc0 += __builtin_elementwise_max(qq + n0lo, zero);
                acc1 += __builtin_elementwise_max(qq + n0hi, zero);
                acc2 += __builtin_elementwise_max(qq + n1lo, zero);
                acc3 += __builtin_elementwise_max(qq + n1hi, zero);
            }
        }
    }

    const v2f accv = (acc0 + acc1) + (acc2 + acc3);
    float acc = accv.x + accv.y;

    // ---- Wave shuffle reduce, then across the 4 waves, single store.
    #pragma unroll
    for (int off = 32; off > 0; off >>= 1) acc += __shfl_down(acc, off, 64);
    if (lane == 0) red[wave] = acc;
    __syncthreads();

    if (tid == 0) {
        const float s = (red[0] + red[1]) + (red[2] + red[3]);
        const float n_pairs = (float)n_pos * (float)n_neg;
        ws[b] = s / fmaxf(n_pairs, 1.0f);
    }
}

// Kernel 2: deterministic reduction of BATCH per-sample losses -> mean.
// One float4 per thread (256 x 4 = 1024).
__global__ __launch_bounds__(NTHREADS) void reduce_batch(
    const float* __restrict__ ws, float* __restrict__ out)
{
    __shared__ float red[NTHREADS / 64];
    const int tid  = threadIdx.x;
    const int lane = tid & 63;
    const int wave = tid >> 6;

    const float4 v = reinterpret_cast<const float4*>(ws)[tid];
    float acc = (v.x + v.y) + (v.z + v.w);

    #pragma unroll
    for (int off = 32; off > 0; off >>= 1) acc += __shfl_down(acc, off, 64);
    if (lane == 0) red[wave] = acc;
    __syncthreads();

    if (tid == 0) {
        out[0] = ((red[0] + red[1]) + (red[2] + red[3])) * (1.0f / (float)BATCH);
    }
}

extern "C" void kernel_launch(void* const* d_in, const int* in_sizes, int n_in,
                              void* d_out, int out_size, void* d_ws, size_t ws_size,
                              hipStream_t stream) {
    const float* scores = (const float*)d_in[0];
    const int*   labels = (const int*)d_in[1];
    float*       out    = (float*)d_out;
    float*       ws     = (float*)d_ws;   // BATCH floats of scratch

    per_sample_loss<<<BATCH, NTHREADS, 0, stream>>>(scores, labels, ws);
    reduce_batch<<<1, NTHREADS, 0, stream>>>(ws, out);
}